// Round 6
// baseline (213.577 us; speedup 1.0000x reference)
//
#include <hip/hip_runtime.h>

namespace {

constexpr int BD = 2;
constexpr int DD = 160, HH = 192, WW = 224;
constexpr float INV_WIN = 1.0f / 729.0f;
constexpr float EPSV = 1e-5f;

constexpr int TH = 16, TW = 16;          // output tile (H x W) — R0 shape (best measured)
constexpr int DC = 16;                   // output planes per d-chunk — R0 value (R5's 32 ballooned VGPR)
constexpr int NREAL = DC + 8;            // 24 plane steps = 12 pairs
constexpr int NPAIR = NREAL / 2;         // 12; superstep loop runs 13, FULLY unrolled
constexpr int NCH = DD / DC;             // 10
constexpr int GX = WW / TW;              // 14
constexpr int GY = HH / TH;              // 12
constexpr int GZ = BD * NCH;             // 20
constexpr int NBLK = GX * GY * GZ;       // 3360 (13 blocks/CU: deep refill pipeline)
constexpr int NXCD = 8;
constexpr int CPX = NBLK / NXCD;         // 420 (3360 % 8 == 0 -> bijective swizzle)
constexpr double NTOT = (double)BD * DD * HH * WW;

// srow: [plane][field][w*28 + row], rows 0..23 contiguous (pad 28). SINGLE
// buffered (R6): S2 moved to phase B makes the dbuf unnecessary (see hazard
// matrix below). SR_FS=452 (f-shift /4=113==1 mod 8), SR_PL=2280 (==8 mod 32).
// Audited: S2 b32 scatter 2/bank; S3 b128 reads uniform /quad.
constexpr int SR_FS = 452;
constexpr int SR_PL = 2280;
// scol: [plane][field][w*20 + o]. SC_FS=324, SC_PL=1620. S3 b128 writes
// uniform /quad; S4 b32 reads exactly 2/bank.
constexpr int SC_FS = 324;
constexpr int SC_PL = 1620;

} // namespace

// R6: R0 epoch shape (13 pair-supersteps, 2 barriers/epoch, identical VALU
// work & audited LDS layouts) at 5 blocks/CU residency (was 3).
//   Phase A: prefetch-issue | S3(ss-1): srow -> scol
//   barrier C
//   Phase B: S2(ss) -> srow | S4(ss-1): scol -> ring/emit
//   barrier E
// Hazards (all two-phase, single srow buffer):
//   S3(ss-1) R srow  vs S2(ss) W srow   : C between            OK
//   S2(ss)  W srow   vs S3(ss) R srow   : E between            OK
//   S3(ss-1) W scol  vs S4(ss-1) R scol : C between            OK
//   S4(ss-1) R scol  vs S3(ss) W scol   : E between            OK
// LDS: 2280*2*4 (srow, 2 planes) + 1620*2*4 (scol) + 16 = 31216 B
//   -> 5 blocks/CU = 20 waves (R0: 3 blocks/12 waves). Session model:
//   dur x VALUBusy ~ const (39-46) across R0-R5 => stall-bound; this raises
//   waves/SIMD 3->5 on the SAME work.
// Lessons: R1 no min-waves hint (spill). R2 don't halve epoch work. R3 don't
// one-shot the grid / roll the loop. R4 don't go 512-thread blocks. R5 don't
// deepen unroll past 13 (VGPR 128).
__global__ __launch_bounds__(256)
void ncc_fused(const float* __restrict__ x, const float* __restrict__ y,
               float* __restrict__ bsum) {
  const int tid = threadIdx.x;

  // XCD-chunked swizzle (proven: FETCH 348 -> ~70 MB): each XCD gets a
  // contiguous chunk of (bx,by,zb) so halo re-reads hit same-XCD L2.
  const int lid = (int)blockIdx.x;
  const int nl  = (lid & (NXCD - 1)) * CPX + (lid >> 3);
  const int zb  = nl / (GX * GY);
  const int rem = nl - zb * (GX * GY);
  const int by  = rem / GX;
  const int bx  = rem - by * GX;

  const int w0 = bx * TW;
  const int h0 = by * TH;
  const int b  = zb / NCH;
  const int d0 = (zb - b * NCH) * DC;

  __shared__ __align__(16) float srowF[2 * SR_PL];     // 18240 B (single buf)
  __shared__ __align__(16) float scolF[2 * SC_PL];     // 12960 B
  __shared__ float swsum[4];

  // ---- S2 roles: tids 0..191 = 2 planes x 24 rows x 4 col-segments,
  // 12-wide register window -> 4 sliding 9-tap W-sums x 5 fields.
  const bool s2a = tid < 192;
  const int p2  = tid / 96;
  const int t96 = tid - 96 * p2;
  const int r2  = t96 >> 2;            // input row 0..23
  const int seg = tid & 3;
  const int gh  = h0 - 4 + r2;
  const int gw0 = w0 - 4 + seg * 4;    // 16B aligned
  const bool hok = (unsigned)gh < (unsigned)HH;
  const bool fastw = (gw0 >= 0) && (gw0 + 11 < WW);
  const unsigned plane = (unsigned)HH * WW;

  auto prefetch = [&](int s, float4* vx, float4* vy) {
    const int din = d0 - 4 + s;
    const float4 z = make_float4(0.f, 0.f, 0.f, 0.f);
    vx[0] = vx[1] = vx[2] = z;
    vy[0] = vy[1] = vy[2] = z;
    if (s2a && hok && (s < NREAL) && (din >= 0) && (din < DD)) {
      const unsigned rb = ((unsigned)b * DD + (unsigned)din) * plane + (unsigned)gh * WW;
      if (fastw) {
        const float4* px = (const float4*)(x + rb + gw0);
        const float4* py = (const float4*)(y + rb + gw0);
        vx[0] = px[0]; vx[1] = px[1]; vx[2] = px[2];
        vy[0] = py[0]; vy[1] = py[1]; vy[2] = py[2];
      } else {
        float* fx = (float*)vx;
        float* fy = (float*)vy;
#pragma unroll
        for (int e = 0; e < 12; ++e) {
          const int gw = gw0 + e;
          if ((unsigned)gw < (unsigned)WW) {
            fx[e] = x[rb + gw];
            fy[e] = y[rb + gw];
          }
        }
      }
    }
  };

  // ---- S3 roles: tids 96..255 = 2 planes x 5 fields x 16 w.
  const int t3  = tid - 96;
  const int p3  = t3 / 80;
  const int r3  = t3 - 80 * p3;
  const int f3  = r3 >> 4;
  const int wl3 = r3 & 15;

  const int ow = tid & 15;
  const int oh = tid >> 4;

  // D-ring: 9 slots x 5 fields; slot indices static after full unroll.
  float rg0[9], rg1[9], rg2[9], rg3[9], rg4[9];
#pragma unroll
  for (int k = 0; k < 9; ++k) { rg0[k]=0.f; rg1[k]=0.f; rg2[k]=0.f; rg3[k]=0.f; rg4[k]=0.f; }
  float a0=0.f, a1=0.f, a2=0.f, a3=0.f, a4=0.f;
  float lsum = 0.0f;

  float4 px4[3], py4[3];
  prefetch(p2, px4, py4);               // pair 0

  // Pipelined supersteps: S2 stages pair ss (phase B); S3/S4 consume pair
  // ss-1 (S3 phase A, S4 phase B).
#pragma unroll
  for (int ss = 0; ss <= NPAIR; ++ss) {
    // prefetch pair ss+1 (consumed by S2 in phase B of NEXT superstep)
    float4 nx4[3], ny4[3];
    if (ss + 1 < NPAIR) prefetch(2 * (ss + 1) + p2, nx4, ny4);

    // ---- Phase A. S3 (pair ss-1): H-sums from srow -> scol.
    if (ss >= 1 && tid >= 96) {
      const float* rp = &srowF[p3 * SR_PL + f3 * SR_FS + wl3 * 28];
      float rv[24];
#pragma unroll
      for (int t = 0; t < 6; ++t) *(float4*)&rv[4 * t] = *(const float4*)&rp[4 * t];
      float acc = rv[0];
#pragma unroll
      for (int t = 1; t < 9; ++t) acc += rv[t];
      float ov[16];
      ov[0] = acc;
#pragma unroll
      for (int o = 1; o < 16; ++o) { acc += rv[o + 8] - rv[o - 1]; ov[o] = acc; }
      float* cp = &scolF[p3 * SC_PL + f3 * SC_FS + wl3 * 20];
#pragma unroll
      for (int t = 0; t < 4; ++t)
        *(float4*)&cp[4 * t] = make_float4(ov[4*t], ov[4*t+1], ov[4*t+2], ov[4*t+3]);
    }
    __syncthreads();   // C: scol visible to S4; S3 srow-reads done before S2 overwrites

    // ---- Phase B. S2 (pair ss): W-sums -> srow (safe: S3 read it pre-C).
    if (ss < NPAIR && s2a) {
      float xv[12], yv[12];
#pragma unroll
      for (int k = 0; k < 3; ++k) {
        *(float4*)&xv[4 * k] = px4[k];
        *(float4*)&yv[4 * k] = py4[k];
      }
      float s0=0.f, s1=0.f, s2=0.f, s3=0.f, s4=0.f;
#pragma unroll
      for (int k = 0; k < 9; ++k) {
        s0 += xv[k]; s1 += yv[k];
        s2 = fmaf(xv[k], xv[k], s2);
        s3 = fmaf(yv[k], yv[k], s3);
        s4 = fmaf(xv[k], yv[k], s4);
      }
      float* wb = &srowF[p2 * SR_PL + (seg * 4) * 28 + r2];
      wb[0 * SR_FS] = s0; wb[1 * SR_FS] = s1; wb[2 * SR_FS] = s2;
      wb[3 * SR_FS] = s3; wb[4 * SR_FS] = s4;
#pragma unroll
      for (int t = 1; t < 4; ++t) {
        const float xn = xv[8 + t], xo = xv[t - 1];
        const float yn = yv[8 + t], yo = yv[t - 1];
        s0 += xn - xo;
        s1 += yn - yo;
        s2 += fmaf(xn, xn, -(xo * xo));
        s3 += fmaf(yn, yn, -(yo * yo));
        s4 += fmaf(xn, yn, -(xo * yo));
        float* wt = wb + t * 28;
        wt[0 * SR_FS] = s0; wt[1 * SR_FS] = s1; wt[2 * SR_FS] = s2;
        wt[3 * SR_FS] = s3; wt[4 * SR_FS] = s4;
      }
    }

    // ---- Phase B. S4 (pair ss-1): ring update + emit (all 256 threads).
    // Reads scol only (disjoint from S2's srow writes).
    if (ss >= 1) {
      const int sA  = 2 * (ss - 1);
      const int sB  = sA + 1;
      const int slA = sA % 9;            // compile-time under full unroll
      const int slB = sB % 9;
      const float* cA = &scolF[ow * 20 + oh];
      const float* cB = cA + SC_PL;
      const float gA0 = cA[0*SC_FS], gA1 = cA[1*SC_FS], gA2 = cA[2*SC_FS],
                  gA3 = cA[3*SC_FS], gA4 = cA[4*SC_FS];
      const float gB0 = cB[0*SC_FS], gB1 = cB[1*SC_FS], gB2 = cB[2*SC_FS],
                  gB3 = cB[3*SC_FS], gB4 = cB[4*SC_FS];

      a0 += gA0 - rg0[slA]; rg0[slA] = gA0;
      a1 += gA1 - rg1[slA]; rg1[slA] = gA1;
      a2 += gA2 - rg2[slA]; rg2[slA] = gA2;
      a3 += gA3 - rg3[slA]; rg3[slA] = gA3;
      a4 += gA4 - rg4[slA]; rg4[slA] = gA4;
      if (sA >= 8) {
        const float cross = fmaf(-a0 * INV_WIN, a1, a4);
        const float iv = fmaxf(fmaf(-a0 * INV_WIN, a0, a2), EPSV);
        const float jv = fmaxf(fmaf(-a1 * INV_WIN, a1, a3), EPSV);
        lsum += (cross * cross) / (iv * jv);
      }
      a0 += gB0 - rg0[slB]; rg0[slB] = gB0;
      a1 += gB1 - rg1[slB]; rg1[slB] = gB1;
      a2 += gB2 - rg2[slB]; rg2[slB] = gB2;
      a3 += gB3 - rg3[slB]; rg3[slB] = gB3;
      a4 += gB4 - rg4[slB]; rg4[slB] = gB4;
      if (sB >= 8) {
        const float cross = fmaf(-a0 * INV_WIN, a1, a4);
        const float iv = fmaxf(fmaf(-a0 * INV_WIN, a0, a2), EPSV);
        const float jv = fmaxf(fmaf(-a1 * INV_WIN, a1, a3), EPSV);
        lsum += (cross * cross) / (iv * jv);
      }
    }
    __syncthreads();   // E: S2 srow writes visible to S3(ss+1); S4 scol reads
                       //    done before S3(ss+1) overwrites scol.
    if (ss + 1 < NPAIR) {
#pragma unroll
      for (int k = 0; k < 3; ++k) { px4[k] = nx4[k]; py4[k] = ny4[k]; }
    }
  }

  // ---- block reduction
#pragma unroll
  for (int off = 32; off > 0; off >>= 1) lsum += __shfl_down(lsum, off);
  if ((tid & 63) == 0) swsum[tid >> 6] = lsum;
  __syncthreads();
  if (tid == 0) bsum[nl] = swsum[0] + swsum[1] + swsum[2] + swsum[3];
}

__global__ __launch_bounds__(256)
void ncc_finalize(const float* __restrict__ bsum, float* __restrict__ out) {
  double s = 0.0;
  for (int i = threadIdx.x; i < NBLK; i += 256) s += (double)bsum[i];
#pragma unroll
  for (int off = 32; off > 0; off >>= 1) s += __shfl_down(s, off);
  __shared__ double sh[4];
  if ((threadIdx.x & 63) == 0) sh[threadIdx.x >> 6] = s;
  __syncthreads();
  if (threadIdx.x == 0)
    out[0] = (float)(-(sh[0] + sh[1] + sh[2] + sh[3]) / NTOT);
}

extern "C" void kernel_launch(void* const* d_in, const int* in_sizes, int n_in,
                              void* d_out, int out_size, void* d_ws, size_t ws_size,
                              hipStream_t stream) {
  const float* x = (const float*)d_in[0];
  const float* y = (const float*)d_in[1];
  float* bsum = (float*)d_ws;          // 3360 floats, fully rewritten every call
  float* out  = (float*)d_out;

  ncc_fused<<<dim3(NBLK), dim3(256), 0, stream>>>(x, y, bsum);
  ncc_finalize<<<1, dim3(256), 0, stream>>>(bsum, out);
}

// Round 7
// 212.062 us; speedup vs baseline: 1.0071x; 1.0071x over previous
//
#include <hip/hip_runtime.h>

namespace {

constexpr int BD = 2;
constexpr int DD = 160, HH = 192, WW = 224;
constexpr float INV_WIN = 1.0f / 729.0f;
constexpr float EPSV = 1e-5f;

constexpr int TH = 16, TW = 16;          // output tile (H x W) — R0 shape (best measured)
constexpr int DC = 16;                   // output planes per d-chunk — R0 value
constexpr int NREAL = DC + 8;            // 24 plane steps = 12 pairs
constexpr int NPAIR = NREAL / 2;         // 12; epoch loop runs 14 (S4 delayed 2), FULLY unrolled
constexpr int NCH = DD / DC;             // 10
constexpr int GX = WW / TW;              // 14
constexpr int GY = HH / TH;              // 12
constexpr int GZ = BD * NCH;             // 20
constexpr int NBLK = GX * GY * GZ;       // 3360
constexpr int NXCD = 8;
constexpr int CPX = NBLK / NXCD;         // 420 (3360 % 8 == 0 -> bijective swizzle)
constexpr double NTOT = (double)BD * DD * HH * WW;

// srow: [parity][plane][field][w*28 + row], rows 0..23 (pad 28). SR_FS=452
// (f-shift /4=113==1 mod 8), SR_PL=2280 (==8 mod 32). Audited: S2 b32
// scatter 2/bank; S3 b128 reads uniform /quad.
constexpr int SR_FS = 452;
constexpr int SR_PL = 2280;
// scol: [parity][plane][field][w*20 + o]. SC_FS=324, SC_PL=1620. S3 b128
// writes uniform /quad; S4 b32 reads exactly 2/bank.
constexpr int SC_FS = 324;
constexpr int SC_PL = 1620;

} // namespace

// R7: ONE barrier per epoch (R0 had 2). Evidence: R0-R6 all show
// dur x VALUBusy ~= const 45us with both pipes >=60% idle and occupancy
// NOT tracking the residency cap (R6: cap 5 blk/CU, occ FELL to 19%) —
// waves are parked at barrier drains. 26 drains/block is the only cost
// class never attacked. Structure: parity-dbuf BOTH srow and scol; delay
// S4 by one extra epoch so every producer/consumer pair is separated by
// exactly one barrier:
//   epoch k: [prefetch(k+1) | S4-load pair k-2 from scol[k&1] |
//             S2(k)->srow[k&1] | S3(k-1): srow[(k-1)&1]->scol[(k-1)&1] |
//             S4 ring/emit pair k-2]  -> barrier
// Hazards (1 barrier each): S2(k)W vs S3(k)R srow[k&1] @k+1 OK;
//   S3(k-1)R vs S2(k+1)W srow[(k-1)&1] OK; S3(k-1)W vs S4@k+1 R
//   scol[(k-1)&1] OK; S4@k R vs S3(k)W scol[k&1] @k+1 OK.
// LDS: (2*2*2280 + 2*2*1620)*4 + 16 = 62416 B -> 2 blocks/CU (8 waves).
// Rationale for accepting residency 3->2: R6 proved extra resident waves
// sit parked; this trades them for 42% fewer drain events + 4 independent
// streams per epoch (S4 loads are 2-epochs-stale = zero intra-epoch deps).
// VGPR budget at 2 blk/CU = 256/wave — 14-deep unroll is spill-free.
// Lessons kept: R1 no min-waves hint; R2 don't shrink epoch work; R3 don't
// one-shot grid/roll loop; R4 don't use 512-thread blocks; R5 DC=16.
__global__ __launch_bounds__(256)
void ncc_fused(const float* __restrict__ x, const float* __restrict__ y,
               float* __restrict__ bsum) {
  const int tid = threadIdx.x;

  // XCD-chunked swizzle (FETCH 348 -> ~78 MB, duration-neutral +-4%).
  const int lid = (int)blockIdx.x;
  const int nl  = (lid & (NXCD - 1)) * CPX + (lid >> 3);
  const int zb  = nl / (GX * GY);
  const int rem = nl - zb * (GX * GY);
  const int by  = rem / GX;
  const int bx  = rem - by * GX;

  const int w0 = bx * TW;
  const int h0 = by * TH;
  const int b  = zb / NCH;
  const int d0 = (zb - b * NCH) * DC;

  __shared__ __align__(16) float srowF[2][2 * SR_PL];  // 36480 B (parity x pair)
  __shared__ __align__(16) float scolF[2][2 * SC_PL];  // 25920 B (parity x pair)
  __shared__ float swsum[4];

  // ---- S2 roles: tids 0..191 = 2 planes x 24 rows x 4 col-segments.
  const bool s2a = tid < 192;
  const int p2  = tid / 96;
  const int t96 = tid - 96 * p2;
  const int r2  = t96 >> 2;            // input row 0..23
  const int seg = tid & 3;
  const int gh  = h0 - 4 + r2;
  const int gw0 = w0 - 4 + seg * 4;    // 16B aligned
  const bool hok = (unsigned)gh < (unsigned)HH;
  const bool fastw = (gw0 >= 0) && (gw0 + 11 < WW);
  const unsigned plane = (unsigned)HH * WW;

  auto prefetch = [&](int s, float4* vx, float4* vy) {
    const int din = d0 - 4 + s;
    const float4 z = make_float4(0.f, 0.f, 0.f, 0.f);
    vx[0] = vx[1] = vx[2] = z;
    vy[0] = vy[1] = vy[2] = z;
    if (s2a && hok && (s < NREAL) && (din >= 0) && (din < DD)) {
      const unsigned rb = ((unsigned)b * DD + (unsigned)din) * plane + (unsigned)gh * WW;
      if (fastw) {
        const float4* px = (const float4*)(x + rb + gw0);
        const float4* py = (const float4*)(y + rb + gw0);
        vx[0] = px[0]; vx[1] = px[1]; vx[2] = px[2];
        vy[0] = py[0]; vy[1] = py[1]; vy[2] = py[2];
      } else {
        float* fx = (float*)vx;
        float* fy = (float*)vy;
#pragma unroll
        for (int e = 0; e < 12; ++e) {
          const int gw = gw0 + e;
          if ((unsigned)gw < (unsigned)WW) {
            fx[e] = x[rb + gw];
            fy[e] = y[rb + gw];
          }
        }
      }
    }
  };

  // ---- S3 roles: tids 96..255 = 2 planes x 5 fields x 16 w.
  const int t3  = tid - 96;
  const int p3  = t3 / 80;
  const int r3  = t3 - 80 * p3;
  const int f3  = r3 >> 4;
  const int wl3 = r3 & 15;

  const int ow = tid & 15;
  const int oh = tid >> 4;

  // D-ring: 9 slots x 5 fields; slot indices static after full unroll.
  float rg0[9], rg1[9], rg2[9], rg3[9], rg4[9];
#pragma unroll
  for (int k = 0; k < 9; ++k) { rg0[k]=0.f; rg1[k]=0.f; rg2[k]=0.f; rg3[k]=0.f; rg4[k]=0.f; }
  float a0=0.f, a1=0.f, a2=0.f, a3=0.f, a4=0.f;
  float lsum = 0.0f;

  float4 px4[3], py4[3];
  prefetch(p2, px4, py4);               // pair 0

  // 14 single-barrier epochs: S2 stages pair k; S3 consumes pair k-1;
  // S4 consumes pair k-2 (2-epoch-stale scol -> no intra-epoch deps).
#pragma unroll
  for (int k = 0; k <= NPAIR + 1; ++k) {
    // prefetch pair k+1 (consumed by S2 next epoch)
    float4 nx4[3], ny4[3];
    if (k + 1 < NPAIR) prefetch(2 * (k + 1) + p2, nx4, ny4);

    // ---- S4 loads (pair k-2) from scol[k&1] — written 2 epochs ago, so
    // these can issue immediately and overlap everything below.
    float gA0=0.f, gA1=0.f, gA2=0.f, gA3=0.f, gA4=0.f;
    float gB0=0.f, gB1=0.f, gB2=0.f, gB3=0.f, gB4=0.f;
    if (k >= 2) {
      const float* cA = &scolF[k & 1][ow * 20 + oh];
      const float* cB = cA + SC_PL;
      gA0 = cA[0*SC_FS]; gA1 = cA[1*SC_FS]; gA2 = cA[2*SC_FS];
      gA3 = cA[3*SC_FS]; gA4 = cA[4*SC_FS];
      gB0 = cB[0*SC_FS]; gB1 = cB[1*SC_FS]; gB2 = cB[2*SC_FS];
      gB3 = cB[3*SC_FS]; gB4 = cB[4*SC_FS];
    }

    // ---- S2 (pair k): W-sums -> srow[k&1].
    if (k < NPAIR && s2a) {
      float xv[12], yv[12];
#pragma unroll
      for (int q = 0; q < 3; ++q) {
        *(float4*)&xv[4 * q] = px4[q];
        *(float4*)&yv[4 * q] = py4[q];
      }
      float s0=0.f, s1=0.f, s2=0.f, s3=0.f, s4=0.f;
#pragma unroll
      for (int q = 0; q < 9; ++q) {
        s0 += xv[q]; s1 += yv[q];
        s2 = fmaf(xv[q], xv[q], s2);
        s3 = fmaf(yv[q], yv[q], s3);
        s4 = fmaf(xv[q], yv[q], s4);
      }
      float* wb = &srowF[k & 1][p2 * SR_PL + (seg * 4) * 28 + r2];
      wb[0 * SR_FS] = s0; wb[1 * SR_FS] = s1; wb[2 * SR_FS] = s2;
      wb[3 * SR_FS] = s3; wb[4 * SR_FS] = s4;
#pragma unroll
      for (int t = 1; t < 4; ++t) {
        const float xn = xv[8 + t], xo = xv[t - 1];
        const float yn = yv[8 + t], yo = yv[t - 1];
        s0 += xn - xo;
        s1 += yn - yo;
        s2 += fmaf(xn, xn, -(xo * xo));
        s3 += fmaf(yn, yn, -(yo * yo));
        s4 += fmaf(xn, yn, -(xo * yo));
        float* wt = wb + t * 28;
        wt[0 * SR_FS] = s0; wt[1 * SR_FS] = s1; wt[2 * SR_FS] = s2;
        wt[3 * SR_FS] = s3; wt[4 * SR_FS] = s4;
      }
    }

    // ---- S3 (pair k-1): H-sums srow[(k-1)&1] -> scol[(k-1)&1].
    // Concurrent with S2 (different srow parity) and S4 (different scol parity).
    if (k >= 1 && k <= NPAIR && tid >= 96) {
      const float* rp = &srowF[(k - 1) & 1][p3 * SR_PL + f3 * SR_FS + wl3 * 28];
      float rv[24];
#pragma unroll
      for (int t = 0; t < 6; ++t) *(float4*)&rv[4 * t] = *(const float4*)&rp[4 * t];
      float acc = rv[0];
#pragma unroll
      for (int t = 1; t < 9; ++t) acc += rv[t];
      float ov[16];
      ov[0] = acc;
#pragma unroll
      for (int o = 1; o < 16; ++o) { acc += rv[o + 8] - rv[o - 1]; ov[o] = acc; }
      float* cp = &scolF[(k - 1) & 1][p3 * SC_PL + f3 * SC_FS + wl3 * 20];
#pragma unroll
      for (int t = 0; t < 4; ++t)
        *(float4*)&cp[4 * t] = make_float4(ov[4*t], ov[4*t+1], ov[4*t+2], ov[4*t+3]);
    }

    // ---- S4 (pair k-2): ring update + emit (all 256 threads).
    // Same arithmetic sequence as R0 (exactness preserved).
    if (k >= 2) {
      const int sA  = 2 * (k - 2);
      const int sB  = sA + 1;
      const int slA = sA % 9;            // compile-time under full unroll
      const int slB = sB % 9;

      a0 += gA0 - rg0[slA]; rg0[slA] = gA0;
      a1 += gA1 - rg1[slA]; rg1[slA] = gA1;
      a2 += gA2 - rg2[slA]; rg2[slA] = gA2;
      a3 += gA3 - rg3[slA]; rg3[slA] = gA3;
      a4 += gA4 - rg4[slA]; rg4[slA] = gA4;
      if (sA >= 8) {
        const float cross = fmaf(-a0 * INV_WIN, a1, a4);
        const float iv = fmaxf(fmaf(-a0 * INV_WIN, a0, a2), EPSV);
        const float jv = fmaxf(fmaf(-a1 * INV_WIN, a1, a3), EPSV);
        lsum += (cross * cross) / (iv * jv);
      }
      a0 += gB0 - rg0[slB]; rg0[slB] = gB0;
      a1 += gB1 - rg1[slB]; rg1[slB] = gB1;
      a2 += gB2 - rg2[slB]; rg2[slB] = gB2;
      a3 += gB3 - rg3[slB]; rg3[slB] = gB3;
      a4 += gB4 - rg4[slB]; rg4[slB] = gB4;
      if (sB >= 8) {
        const float cross = fmaf(-a0 * INV_WIN, a1, a4);
        const float iv = fmaxf(fmaf(-a0 * INV_WIN, a0, a2), EPSV);
        const float jv = fmaxf(fmaf(-a1 * INV_WIN, a1, a3), EPSV);
        lsum += (cross * cross) / (iv * jv);
      }
    }

    __syncthreads();   // the ONE barrier: orders every producer/consumer
                       // pair listed in the header hazard audit.
    if (k + 1 < NPAIR) {
#pragma unroll
      for (int q = 0; q < 3; ++q) { px4[q] = nx4[q]; py4[q] = ny4[q]; }
    }
  }

  // ---- block reduction
#pragma unroll
  for (int off = 32; off > 0; off >>= 1) lsum += __shfl_down(lsum, off);
  if ((tid & 63) == 0) swsum[tid >> 6] = lsum;
  __syncthreads();
  if (tid == 0) bsum[nl] = swsum[0] + swsum[1] + swsum[2] + swsum[3];
}

__global__ __launch_bounds__(256)
void ncc_finalize(const float* __restrict__ bsum, float* __restrict__ out) {
  double s = 0.0;
  for (int i = threadIdx.x; i < NBLK; i += 256) s += (double)bsum[i];
#pragma unroll
  for (int off = 32; off > 0; off >>= 1) s += __shfl_down(s, off);
  __shared__ double sh[4];
  if ((threadIdx.x & 63) == 0) sh[threadIdx.x >> 6] = s;
  __syncthreads();
  if (threadIdx.x == 0)
    out[0] = (float)(-(sh[0] + sh[1] + sh[2] + sh[3]) / NTOT);
}

extern "C" void kernel_launch(void* const* d_in, const int* in_sizes, int n_in,
                              void* d_out, int out_size, void* d_ws, size_t ws_size,
                              hipStream_t stream) {
  const float* x = (const float*)d_in[0];
  const float* y = (const float*)d_in[1];
  float* bsum = (float*)d_ws;          // 3360 floats, fully rewritten every call
  float* out  = (float*)d_out;

  ncc_fused<<<dim3(NBLK), dim3(256), 0, stream>>>(x, y, bsum);
  ncc_finalize<<<1, dim3(256), 0, stream>>>(bsum, out);
}

// Round 8
// 193.519 us; speedup vs baseline: 1.1036x; 1.0958x over previous
//
#include <hip/hip_runtime.h>

namespace {

constexpr int BD = 2;
constexpr int DD = 160, HH = 192, WW = 224;
constexpr float INV_WIN = 1.0f / 729.0f;
constexpr float EPSV = 1e-5f;

constexpr int TH = 16, TW = 16;          // output tile (H x W)
constexpr int DC = 16;                   // output planes per d-chunk
constexpr int NREAL = DC + 8;            // 24 plane steps = 12 pairs
constexpr int NPAIR = NREAL / 2;         // 12; superstep loop runs 13 (pipelined)
constexpr int NCH = DD / DC;             // 10
constexpr int GX = WW / TW;              // 14
constexpr int GY = HH / TH;              // 12
constexpr int GZ = BD * NCH;             // 20
constexpr int NBLK = GX * GY * GZ;       // 3360
constexpr int NXCD = 8;
constexpr int CPX = NBLK / NXCD;         // 420 (3360 % 8 == 0 -> bijective swizzle)
constexpr double NTOT = (double)BD * DD * HH * WW;

// srow: [buf][plane][field][w*28 + row], rows 0..23 contiguous (pad 28).
// SR_FS=452 (f-shift /4=113==1 mod 8), SR_PL=2280 (==8 mod 32). Audited:
// S2 b32 scatter 2/bank (b32 floor); S3 b128 reads uniform /quad.
constexpr int SR_FS = 452;
constexpr int SR_PL = 2280;
// scol: [plane][field][w*20 + o]. SC_FS=324, SC_PL=1620. S3 b128 writes
// uniform /quad; S4 b32 reads exactly 2/bank (b32 floor).
constexpr int SC_FS = 324;
constexpr int SC_PL = 1620;

} // namespace

// EXACT Round-0 baseline structure (best measured: fused 115.0 us) + XCD
// swizzle (the one delta counter-proven beneficial/neutral: FETCH 348->78 MB
// across 3 kernels). SESSION CONCLUSION (R1-R7, all regressed or flat):
//   The kernel is LDS-PIPE-ISSUE-BOUND: ~940 cyc of ds-instruction issue per
//   pair-superstep per block x 13 ss x 13.1 blk/CU ~= 67 us serial LDS-pipe
//   time per CU (+ 2/bank b32 floor conflicts) vs 115 us wall. Duration is
//   invariant to barrier count (R7: 26->15, flat), residency (R6: 3->5
//   blk/CU, flat), epoch merging (R2: 1.65x WORSE), grid shape (R3: 1.6x
//   worse one-shot), block size (R4: 512-thr worse), DC (R5: VGPR balloon).
//   Both transposes (srow: S2 b32-W/S3 b128-R; scol: S3 b128-W/S4 b32-R)
//   are at their width-optimal orientation — flipping either is net-negative
//   (transpose forces one narrow side; wave-masking taxes any retiling).
//   dur x VALUBusy ~= 45 us held across all 8 measurements.
// DO NOT: add min-waves launch_bounds (R1: ring spill, 3x); shrink epoch
// work (R2); roll the superstep loop or one-shot the grid (R3); grow the
// block (R4); deepen the unroll past 13 (R5: VGPR 128).
__global__ __launch_bounds__(256)
void ncc_fused(const float* __restrict__ x, const float* __restrict__ y,
               float* __restrict__ bsum) {
  const int tid = threadIdx.x;

  // XCD-chunked swizzle: each XCD gets a contiguous chunk of (bx,by,zb) so
  // halo re-reads of neighboring tiles hit the same-XCD L2 (~200cy) instead
  // of HBM (~900cy).
  const int lid = (int)blockIdx.x;
  const int nl  = (lid & (NXCD - 1)) * CPX + (lid >> 3);
  const int zb  = nl / (GX * GY);
  const int rem = nl - zb * (GX * GY);
  const int by  = rem / GX;
  const int bx  = rem - by * GX;

  const int w0 = bx * TW;
  const int h0 = by * TH;
  const int b  = zb / NCH;
  const int d0 = (zb - b * NCH) * DC;

  __shared__ __align__(16) float srowF[2][2 * SR_PL];  // 36480 B (pair dbuf)
  __shared__ __align__(16) float scolF[2 * SC_PL];     // 12960 B
  __shared__ float swsum[4];

  // ---- S2 roles: tids 0..191 = 2 planes x 24 rows x 4 col-segments,
  // 12-wide register window -> 4 sliding 9-tap W-sums x 5 fields.
  const bool s2a = tid < 192;
  const int p2  = tid / 96;
  const int t96 = tid - 96 * p2;
  const int r2  = t96 >> 2;            // input row 0..23
  const int seg = tid & 3;
  const int gh  = h0 - 4 + r2;
  const int gw0 = w0 - 4 + seg * 4;    // 16B aligned
  const bool hok = (unsigned)gh < (unsigned)HH;
  const bool fastw = (gw0 >= 0) && (gw0 + 11 < WW);
  const unsigned plane = (unsigned)HH * WW;

  auto prefetch = [&](int s, float4* vx, float4* vy) {
    const int din = d0 - 4 + s;
    const float4 z = make_float4(0.f, 0.f, 0.f, 0.f);
    vx[0] = vx[1] = vx[2] = z;
    vy[0] = vy[1] = vy[2] = z;
    if (s2a && hok && (s < NREAL) && (din >= 0) && (din < DD)) {
      const unsigned rb = ((unsigned)b * DD + (unsigned)din) * plane + (unsigned)gh * WW;
      if (fastw) {
        const float4* px = (const float4*)(x + rb + gw0);
        const float4* py = (const float4*)(y + rb + gw0);
        vx[0] = px[0]; vx[1] = px[1]; vx[2] = px[2];
        vy[0] = py[0]; vy[1] = py[1]; vy[2] = py[2];
      } else {
        float* fx = (float*)vx;
        float* fy = (float*)vy;
#pragma unroll
        for (int e = 0; e < 12; ++e) {
          const int gw = gw0 + e;
          if ((unsigned)gw < (unsigned)WW) {
            fx[e] = x[rb + gw];
            fy[e] = y[rb + gw];
          }
        }
      }
    }
  };

  // ---- S3 roles: tids 96..255 = 2 planes x 5 fields x 16 w (wave balance:
  // wave0 S2-only, wave3 S3-only, waves1-2 mixed).
  const int t3  = tid - 96;
  const int p3  = t3 / 80;
  const int r3  = t3 - 80 * p3;
  const int f3  = r3 >> 4;
  const int wl3 = r3 & 15;

  const int ow = tid & 15;
  const int oh = tid >> 4;

  // D-ring: 9 slots x 5 fields; slot indices static after full unroll.
  float rg0[9], rg1[9], rg2[9], rg3[9], rg4[9];
#pragma unroll
  for (int k = 0; k < 9; ++k) { rg0[k]=0.f; rg1[k]=0.f; rg2[k]=0.f; rg3[k]=0.f; rg4[k]=0.f; }
  float a0=0.f, a1=0.f, a2=0.f, a3=0.f, a4=0.f;
  float lsum = 0.0f;

  float4 px4[3], py4[3];
  prefetch(p2, px4, py4);               // pair 0

  // Pipelined supersteps: S2 stages pair ss; S3/S4 consume pair ss-1.
#pragma unroll
  for (int ss = 0; ss <= NPAIR; ++ss) {
    // prefetch pair ss+1 (consumed by S2 next superstep)
    float4 nx4[3], ny4[3];
    if (ss + 1 < NPAIR) prefetch(2 * (ss + 1) + p2, nx4, ny4);

    // ---- S2 (pair ss): W-sums -> srow[ss&1]. Independent of S3 below.
    if (ss < NPAIR && s2a) {
      float xv[12], yv[12];
#pragma unroll
      for (int k = 0; k < 3; ++k) {
        *(float4*)&xv[4 * k] = px4[k];
        *(float4*)&yv[4 * k] = py4[k];
      }
      float s0=0.f, s1=0.f, s2=0.f, s3=0.f, s4=0.f;
#pragma unroll
      for (int k = 0; k < 9; ++k) {
        s0 += xv[k]; s1 += yv[k];
        s2 = fmaf(xv[k], xv[k], s2);
        s3 = fmaf(yv[k], yv[k], s3);
        s4 = fmaf(xv[k], yv[k], s4);
      }
      float* wb = &srowF[ss & 1][p2 * SR_PL + (seg * 4) * 28 + r2];
      wb[0 * SR_FS] = s0; wb[1 * SR_FS] = s1; wb[2 * SR_FS] = s2;
      wb[3 * SR_FS] = s3; wb[4 * SR_FS] = s4;
#pragma unroll
      for (int t = 1; t < 4; ++t) {
        const float xn = xv[8 + t], xo = xv[t - 1];
        const float yn = yv[8 + t], yo = yv[t - 1];
        s0 += xn - xo;
        s1 += yn - yo;
        s2 += fmaf(xn, xn, -(xo * xo));
        s3 += fmaf(yn, yn, -(yo * yo));
        s4 += fmaf(xn, yn, -(xo * yo));
        float* wt = wb + t * 28;
        wt[0 * SR_FS] = s0; wt[1 * SR_FS] = s1; wt[2 * SR_FS] = s2;
        wt[3 * SR_FS] = s3; wt[4 * SR_FS] = s4;
      }
    }

    // ---- S3 (pair ss-1): H-sums from srow[(ss-1)&1] -> scol.
    // No barrier needed vs S2: different srow buffer (written last superstep,
    // separated by barrier E(ss-1)).
    if (ss >= 1 && tid >= 96) {
      const float* rp = &srowF[(ss - 1) & 1][p3 * SR_PL + f3 * SR_FS + wl3 * 28];
      float rv[24];
#pragma unroll
      for (int t = 0; t < 6; ++t) *(float4*)&rv[4 * t] = *(const float4*)&rp[4 * t];
      float acc = rv[0];
#pragma unroll
      for (int t = 1; t < 9; ++t) acc += rv[t];
      float ov[16];
      ov[0] = acc;
#pragma unroll
      for (int o = 1; o < 16; ++o) { acc += rv[o + 8] - rv[o - 1]; ov[o] = acc; }
      float* cp = &scolF[p3 * SC_PL + f3 * SC_FS + wl3 * 20];
#pragma unroll
      for (int t = 0; t < 4; ++t)
        *(float4*)&cp[4 * t] = make_float4(ov[4*t], ov[4*t+1], ov[4*t+2], ov[4*t+3]);
    }
    __syncthreads();   // C: scol visible (also orders S2 writes vs next S3)

    // ---- S4 (pair ss-1): ring update + emit (all 256 threads)
    if (ss >= 1) {
      const int sA  = 2 * (ss - 1);
      const int sB  = sA + 1;
      const int slA = sA % 9;
      const int slB = sB % 9;
      const float* cA = &scolF[ow * 20 + oh];
      const float* cB = cA + SC_PL;
      const float gA0 = cA[0*SC_FS], gA1 = cA[1*SC_FS], gA2 = cA[2*SC_FS],
                  gA3 = cA[3*SC_FS], gA4 = cA[4*SC_FS];
      const float gB0 = cB[0*SC_FS], gB1 = cB[1*SC_FS], gB2 = cB[2*SC_FS],
                  gB3 = cB[3*SC_FS], gB4 = cB[4*SC_FS];

      a0 += gA0 - rg0[slA]; rg0[slA] = gA0;
      a1 += gA1 - rg1[slA]; rg1[slA] = gA1;
      a2 += gA2 - rg2[slA]; rg2[slA] = gA2;
      a3 += gA3 - rg3[slA]; rg3[slA] = gA3;
      a4 += gA4 - rg4[slA]; rg4[slA] = gA4;
      if (sA >= 8) {
        const float cross = fmaf(-a0 * INV_WIN, a1, a4);
        const float iv = fmaxf(fmaf(-a0 * INV_WIN, a0, a2), EPSV);
        const float jv = fmaxf(fmaf(-a1 * INV_WIN, a1, a3), EPSV);
        lsum += (cross * cross) / (iv * jv);
      }
      a0 += gB0 - rg0[slB]; rg0[slB] = gB0;
      a1 += gB1 - rg1[slB]; rg1[slB] = gB1;
      a2 += gB2 - rg2[slB]; rg2[slB] = gB2;
      a3 += gB3 - rg3[slB]; rg3[slB] = gB3;
      a4 += gB4 - rg4[slB]; rg4[slB] = gB4;
      if (sB >= 8) {
        const float cross = fmaf(-a0 * INV_WIN, a1, a4);
        const float iv = fmaxf(fmaf(-a0 * INV_WIN, a0, a2), EPSV);
        const float jv = fmaxf(fmaf(-a1 * INV_WIN, a1, a3), EPSV);
        lsum += (cross * cross) / (iv * jv);
      }
    }
    __syncthreads();   // E: S4 scol-reads done before S3(ss+1) overwrites;
                       //    S2(ss) srow writes visible to S3(ss+1).
    if (ss + 1 < NPAIR) {
#pragma unroll
      for (int k = 0; k < 3; ++k) { px4[k] = nx4[k]; py4[k] = ny4[k]; }
    }
  }

  // ---- block reduction
#pragma unroll
  for (int off = 32; off > 0; off >>= 1) lsum += __shfl_down(lsum, off);
  if ((tid & 63) == 0) swsum[tid >> 6] = lsum;
  __syncthreads();
  if (tid == 0) bsum[nl] = swsum[0] + swsum[1] + swsum[2] + swsum[3];
}

__global__ __launch_bounds__(256)
void ncc_finalize(const float* __restrict__ bsum, float* __restrict__ out) {
  double s = 0.0;
  for (int i = threadIdx.x; i < NBLK; i += 256) s += (double)bsum[i];
#pragma unroll
  for (int off = 32; off > 0; off >>= 1) s += __shfl_down(s, off);
  __shared__ double sh[4];
  if ((threadIdx.x & 63) == 0) sh[threadIdx.x >> 6] = s;
  __syncthreads();
  if (threadIdx.x == 0)
    out[0] = (float)(-(sh[0] + sh[1] + sh[2] + sh[3]) / NTOT);
}

extern "C" void kernel_launch(void* const* d_in, const int* in_sizes, int n_in,
                              void* d_out, int out_size, void* d_ws, size_t ws_size,
                              hipStream_t stream) {
  const float* x = (const float*)d_in[0];
  const float* y = (const float*)d_in[1];
  float* bsum = (float*)d_ws;          // 3360 floats, fully rewritten every call
  float* out  = (float*)d_out;

  dim3 grid(NBLK);
  ncc_fused<<<grid, dim3(256), 0, stream>>>(x, y, bsum);
  ncc_finalize<<<1, dim3(256), 0, stream>>>(bsum, out);
}